// Round 3
// baseline (14562.155 us; speedup 1.0000x reference)
//
#include <hip/hip_runtime.h>
#include <hip/hip_bf16.h>

#define SEQ   512
#define BATCH 128
#define XD    256
#define PHID  512
#define RD    256
#define OUTD  256
#define NBLK  48

typedef __attribute__((ext_vector_type(8))) short short8;
typedef __attribute__((ext_vector_type(4))) float floatx4;
typedef __attribute__((ext_vector_type(4))) unsigned int uintx4;

#define MFMA(a, b, c) __builtin_amdgcn_mfma_f32_16x16x32_bf16((a), (b), (c), 0, 0, 0)

__device__ inline short8 ldg8(const __hip_bfloat16* p) {       // cached (x, LDS)
    return *reinterpret_cast<const short8*>(p);
}
// Device-coherent 16B load: volatile -> global_load_dwordx4 sc0 sc1 (bypasses
// L1/L2, reads the LLC coherent point; no buffer_inv needed anywhere).
__device__ inline short8 ldv16(const __hip_bfloat16* p) {
    union { uintx4 u; short8 s; } c;
    c.u = *reinterpret_cast<const volatile uintx4*>(p);
    return c.s;
}
// Device-coherent 2B store (write-through to LLC).
__device__ inline void stv2(__hip_bfloat16* p, float v) {
    *reinterpret_cast<volatile __hip_bfloat16*>(p) = __float2bfloat16(v);
}
__device__ inline int flagld(const int* p) {
    return __hip_atomic_load(p, __ATOMIC_RELAXED, __HIP_MEMORY_SCOPE_AGENT);
}
__device__ inline void flagst(int* p, int v) {
    __hip_atomic_store(p, v, __ATOMIC_RELAXED, __HIP_MEMORY_SCOPE_AGENT);
}
// Drain all outstanding vmem (sc-flagged stores ack from the coherent point,
// so vmcnt(0) == globally visible). Memory clobber pins ordering vs the flag.
__device__ inline void drain() { asm volatile("s_waitcnt vmcnt(0)" ::: "memory"); }

__global__ void convert_x(const float* __restrict__ x, __hip_bfloat16* __restrict__ xbf) {
    const int gid = blockIdx.x * blockDim.x + threadIdx.x;
    const float4 v = reinterpret_cast<const float4*>(x)[gid];
    __hip_bfloat16* d = xbf + 4 * (size_t)gid;
    d[0] = __float2bfloat16(v.x); d[1] = __float2bfloat16(v.y);
    d[2] = __float2bfloat16(v.z); d[3] = __float2bfloat16(v.w);
}

// 48 persistent blocks x 256 threads; per-WAVE flags (64 per stage), no
// __syncthreads and no threadfence in the steady-state loop.
//   bid  0..15 : phi-blocks — 32 cols of phi; x-part GEMM overlaps the r-wait
//   bid 16..31 : s-blocks   — 16 cols of r;   s_a = mu_a @ W1_a^T in regs
//   bid 32..47 : o-blocks   — 16 cols of out; o_a = mu_a @ Wo_a^T in regs
// Flag idx = producer_block*4 + wave (wave w owns batch rows [32w, 32w+32)).
__global__ void __launch_bounds__(256) sru_pipe(
    const float* __restrict__ W1, const float* __restrict__ W2,
    const float* __restrict__ Wo,
    const float* __restrict__ b1, const float* __restrict__ b2,
    const float* __restrict__ bo,
    const __hip_bfloat16* __restrict__ xbf,
    __hip_bfloat16* __restrict__ rbf,
    __hip_bfloat16* __restrict__ phib,
    float* __restrict__ out, int* __restrict__ ctrl)
{
    __shared__ __hip_bfloat16 wlds[32768];   // 64 KB
    const int bid  = blockIdx.x;
    const int tid  = threadIdx.x;
    const int wave = tid >> 6;
    const int lane = tid & 63;
    const int quad = lane >> 4;
    const int lrow = lane & 15;
    const int m0   = wave * 32;
    int* rfl = ctrl;         // 64 flags
    int* pfl = ctrl + 64;    // 64 flags
    int* ofl = ctrl + 128;   // 64 flags
    const float pre[4]  = {0.f, 1.f, 9.f, 99.f};    // alpha/(1-alpha)
    const float post[4] = {1.f, 0.5f, 0.1f, 0.01f}; // (1-alpha)

    if (bid < 16) {
        // ================= phi-block =================
        const int j0 = bid * 32;
        for (int i = tid * 4; i < 2 * 32 * 256; i += 1024) {
            const int part = i >> 13, rem = i & 8191;
            const int n = rem >> 8, k = rem & 255;
            const float4 v = *reinterpret_cast<const float4*>(
                &W2[(j0 + n) * (XD + RD) + part * 256 + k]);
            __hip_bfloat16* dst = &wlds[(((part * 32 + (k >> 3)) * 32 + n) << 3) + (k & 7)];
            dst[0] = __float2bfloat16(v.x); dst[1] = __float2bfloat16(v.y);
            dst[2] = __float2bfloat16(v.z); dst[3] = __float2bfloat16(v.w);
        }
        __syncthreads();
        const float bj0 = b2[j0 + lrow];
        const float bj1 = b2[j0 + 16 + lrow];
        #pragma unroll 1
        for (int t = 0; t < SEQ; ++t) {
            floatx4 acc[2][2] = {};
            // x-part (cached loads; no dependency on r_t) — overlaps the wait
            const __hip_bfloat16* xt = xbf + (size_t)(t * BATCH + m0) * XD;
            #pragma unroll
            for (int k = 0; k < XD; k += 32) {
                const short8 a0 = ldg8(xt + lrow * XD + k + 8 * quad);
                const short8 a1 = ldg8(xt + (16 + lrow) * XD + k + 8 * quad);
                #pragma unroll
                for (int j2 = 0; j2 < 2; ++j2) {
                    const short8 b = ldg8(&wlds[((((k >> 3) + quad) * 32 + j2 * 16 + lrow) << 3)]);
                    acc[0][j2] = MFMA(a0, b, acc[0][j2]);
                    acc[1][j2] = MFMA(a1, b, acc[1][j2]);
                }
            }
            // wait r_t (16 s-waves for rows m0..m0+32) + o back-pressure on ring
            if (lane < 16) {
                const int* f = &rfl[lane * 4 + wave];
                while (flagld(f) < t + 1) __builtin_amdgcn_s_sleep(1);
            } else if (lane < 32) {
                const int* f = &ofl[(lane - 16) * 4 + wave];
                while (flagld(f) < t - 3) __builtin_amdgcn_s_sleep(1);
            }
            // r-part (coherent loads)
            #pragma unroll
            for (int k = 0; k < RD; k += 32) {
                const short8 a0 = ldv16(rbf + (m0 + lrow) * RD + k + 8 * quad);
                const short8 a1 = ldv16(rbf + (m0 + 16 + lrow) * RD + k + 8 * quad);
                #pragma unroll
                for (int j2 = 0; j2 < 2; ++j2) {
                    const short8 b = ldg8(&wlds[(((32 + (k >> 3) + quad) * 32 + j2 * 16 + lrow) << 3)]);
                    acc[0][j2] = MFMA(a0, b, acc[0][j2]);
                    acc[1][j2] = MFMA(a1, b, acc[1][j2]);
                }
            }
            __hip_bfloat16* pb = phib + (size_t)(t & 3) * BATCH * PHID;
            #pragma unroll
            for (int h = 0; h < 2; ++h)
                #pragma unroll
                for (int j2 = 0; j2 < 2; ++j2)
                    #pragma unroll
                    for (int i = 0; i < 4; ++i) {
                        const int row = m0 + 16 * h + quad * 4 + i;
                        const float v = (h ? acc[1][j2][i] : acc[0][j2][i]) + (j2 ? bj1 : bj0);
                        stv2(&pb[row * PHID + j0 + j2 * 16 + lrow], fmaxf(v, 0.f));
                    }
            drain();
            if (lane == 0) flagst(&pfl[bid * 4 + wave], t + 1);
        }
    } else if (bid < 32) {
        // ================= s-block =================
        const int sb = bid - 16, j0 = sb * 16;
        for (int i = tid * 4; i < 4 * 16 * 512; i += 1024) {
            const int a = i >> 13, rem = i & 8191;
            const int n = rem >> 9, k = rem & 511;
            const float4 v = *reinterpret_cast<const float4*>(
                &W1[(j0 + n) * 2048 + a * 512 + k]);
            __hip_bfloat16* dst = &wlds[(((a * 64 + (k >> 3)) * 16 + n) << 3) + (k & 7)];
            dst[0] = __float2bfloat16(v.x); dst[1] = __float2bfloat16(v.y);
            dst[2] = __float2bfloat16(v.z); dst[3] = __float2bfloat16(v.w);
        }
        __syncthreads();
        const float bjv = b1[j0 + lrow];
        floatx4 s[4][2] = {};
        // publish r_0 = relu(b1)
        {
            const float rv = fmaxf(bjv, 0.f);
            #pragma unroll
            for (int h = 0; h < 2; ++h)
                #pragma unroll
                for (int i = 0; i < 4; ++i)
                    stv2(&rbf[(m0 + 16 * h + quad * 4 + i) * RD + j0 + lrow], rv);
            drain();
            if (lane == 0) flagst(&rfl[sb * 4 + wave], 1);
        }
        #pragma unroll 1
        for (int t = 0; t < SEQ; ++t) {
            if (lane < 16) {
                const int* f = &pfl[lane * 4 + wave];
                while (flagld(f) < t + 1) __builtin_amdgcn_s_sleep(1);
            }
            #pragma unroll
            for (int a = 0; a < 4; ++a) { s[a][0] *= pre[a]; s[a][1] *= pre[a]; }
            const __hip_bfloat16* pb = phib + (size_t)(t & 3) * BATCH * PHID;
            #pragma unroll 4
            for (int k = 0; k < PHID; k += 32) {
                const short8 a0 = ldv16(pb + (m0 + lrow) * PHID + k + 8 * quad);
                const short8 a1 = ldv16(pb + (m0 + 16 + lrow) * PHID + k + 8 * quad);
                #pragma unroll
                for (int a = 0; a < 4; ++a) {
                    const short8 b = ldg8(&wlds[(((a * 64 + (k >> 3) + quad) * 16 + lrow) << 3)]);
                    s[a][0] = MFMA(a0, b, s[a][0]);
                    s[a][1] = MFMA(a1, b, s[a][1]);
                }
            }
            #pragma unroll
            for (int a = 0; a < 4; ++a) { s[a][0] *= post[a]; s[a][1] *= post[a]; }
            if (t < SEQ - 1) {
                #pragma unroll
                for (int h = 0; h < 2; ++h)
                    #pragma unroll
                    for (int i = 0; i < 4; ++i) {
                        const float rv = s[0][h][i] + s[1][h][i] + s[2][h][i] + s[3][h][i] + bjv;
                        stv2(&rbf[(m0 + 16 * h + quad * 4 + i) * RD + j0 + lrow], fmaxf(rv, 0.f));
                    }
                drain();
                if (lane == 0) flagst(&rfl[sb * 4 + wave], t + 2);
            }
        }
    } else {
        // ================= o-block =================
        const int ob = bid - 32, j0 = ob * 16;
        for (int i = tid * 4; i < 4 * 16 * 512; i += 1024) {
            const int a = i >> 13, rem = i & 8191;
            const int n = rem >> 9, k = rem & 511;
            const float4 v = *reinterpret_cast<const float4*>(
                &Wo[(j0 + n) * 2048 + a * 512 + k]);
            __hip_bfloat16* dst = &wlds[(((a * 64 + (k >> 3)) * 16 + n) << 3) + (k & 7)];
            dst[0] = __float2bfloat16(v.x); dst[1] = __float2bfloat16(v.y);
            dst[2] = __float2bfloat16(v.z); dst[3] = __float2bfloat16(v.w);
        }
        __syncthreads();
        floatx4 o[4][2] = {};
        #pragma unroll 1
        for (int t = 0; t < SEQ; ++t) {
            if (lane < 16) {
                const int* f = &pfl[lane * 4 + wave];
                while (flagld(f) < t + 1) __builtin_amdgcn_s_sleep(1);
            }
            #pragma unroll
            for (int a = 0; a < 4; ++a) { o[a][0] *= pre[a]; o[a][1] *= pre[a]; }
            const __hip_bfloat16* pb = phib + (size_t)(t & 3) * BATCH * PHID;
            #pragma unroll 4
            for (int k = 0; k < PHID; k += 32) {
                const short8 a0 = ldv16(pb + (m0 + lrow) * PHID + k + 8 * quad);
                const short8 a1 = ldv16(pb + (m0 + 16 + lrow) * PHID + k + 8 * quad);
                #pragma unroll
                for (int a = 0; a < 4; ++a) {
                    const short8 b = ldg8(&wlds[(((a * 64 + (k >> 3) + quad) * 16 + lrow) << 3)]);
                    o[a][0] = MFMA(a0, b, o[a][0]);
                    o[a][1] = MFMA(a1, b, o[a][1]);
                }
            }
            #pragma unroll
            for (int a = 0; a < 4; ++a) { o[a][0] *= post[a]; o[a][1] *= post[a]; }
            drain();   // loads retired -> safe to free ring slot
            if (lane == 0) flagst(&ofl[ob * 4 + wave], t + 1);
        }
        const float bjo = bo[j0 + lrow];
        #pragma unroll
        for (int h = 0; h < 2; ++h)
            #pragma unroll
            for (int i = 0; i < 4; ++i) {
                const int row = m0 + 16 * h + quad * 4 + i;
                const float v = o[0][h][i] + o[1][h][i] + o[2][h][i] + o[3][h][i] + bjo;
                out[row * OUTD + j0 + lrow] = fmaxf(v, 0.f);
            }
    }
}

extern "C" void kernel_launch(void* const* d_in, const int* in_sizes, int n_in,
                              void* d_out, int out_size, void* d_ws, size_t ws_size,
                              hipStream_t stream)
{
    const float* x  = (const float*)d_in[0];
    const float* W1 = (const float*)d_in[1];
    const float* b1 = (const float*)d_in[2];
    const float* W2 = (const float*)d_in[3];
    const float* b2 = (const float*)d_in[4];
    const float* Wo = (const float*)d_in[5];
    const float* bo = (const float*)d_in[6];
    float* out = (float*)d_out;
    char* ws = (char*)d_ws;

    constexpr size_t O_CTRL = 0;                                 // 192 int flags
    constexpr size_t O_RBF  = 4096;                              // 128x256 bf16 = 64 KB
    constexpr size_t O_PHI  = O_RBF + (size_t)BATCH * RD * 2;    // 4 x 128x512 bf16
    constexpr size_t O_X    = O_PHI + 4ull * BATCH * PHID * 2;   // 32 MB

    hipMemsetAsync(ws + O_CTRL, 0, 4096, stream);
    convert_x<<<SEQ * BATCH * XD / 4 / 256, 256, 0, stream>>>(
        x, (__hip_bfloat16*)(ws + O_X));
    sru_pipe<<<NBLK, 256, 0, stream>>>(
        W1, W2, Wo, b1, b2, bo,
        (const __hip_bfloat16*)(ws + O_X),
        (__hip_bfloat16*)(ws + O_RBF),
        (__hip_bfloat16*)(ws + O_PHI),
        out, (int*)(ws + O_CTRL));
}

// Round 4
// 8888.808 us; speedup vs baseline: 1.6383x; 1.6383x over previous
//
#include <hip/hip_runtime.h>
#include <hip/hip_bf16.h>

#define SEQ   512
#define BATCH 128
#define XD    256
#define PHID  512
#define RD    256
#define OUTD  256
#define NBLK  48

typedef __attribute__((ext_vector_type(8))) short short8;
typedef __attribute__((ext_vector_type(4))) float floatx4;
typedef unsigned long long u64;

#define MFMA(a, b, c) __builtin_amdgcn_mfma_f32_16x16x32_bf16((a), (b), (c), 0, 0, 0)

__device__ inline short8 ldg8(const __hip_bfloat16* p) {       // cached (x, LDS)
    return *reinterpret_cast<const short8*>(p);
}
// Device-coherent 16B fragment load as TWO relaxed agent-scope 8B atomic loads:
// emits global_load_dwordx2 with sc1 (L2 bypass -> LLC coherent point), and --
// unlike volatile -- NO s_waitcnt is inserted between them, so all loads in a
// k-loop stay concurrently in flight.
__device__ inline short8 lda16(const __hip_bfloat16* p) {
    union { u64 u[2]; short8 s; } c;
    c.u[0] = __hip_atomic_load((const u64*)p,     __ATOMIC_RELAXED, __HIP_MEMORY_SCOPE_AGENT);
    c.u[1] = __hip_atomic_load((const u64*)p + 1, __ATOMIC_RELAXED, __HIP_MEMORY_SCOPE_AGENT);
    return c.s;
}
// Device-coherent 2B store (write-through to LLC), relaxed -> no waitcnt.
__device__ inline void sta2(__hip_bfloat16* p, float v) {
    union { __hip_bfloat16 b; unsigned short u; } c;
    c.b = __float2bfloat16(v);
    __hip_atomic_store((unsigned short*)p, c.u, __ATOMIC_RELAXED, __HIP_MEMORY_SCOPE_AGENT);
}
__device__ inline int flagld(const int* p) {
    return __hip_atomic_load(p, __ATOMIC_RELAXED, __HIP_MEMORY_SCOPE_AGENT);
}
__device__ inline void flagst(int* p, int v) {
    __hip_atomic_store(p, v, __ATOMIC_RELAXED, __HIP_MEMORY_SCOPE_AGENT);
}
// Drain all outstanding vmem (sc1 stores ack from the coherent point, so
// vmcnt(0) == globally visible). Memory clobber pins the flag store after it.
__device__ inline void drain() { asm volatile("s_waitcnt vmcnt(0)" ::: "memory"); }
// Compiler-only barrier: keep data loads from being hoisted above flag polls.
__device__ inline void cbar() { asm volatile("" ::: "memory"); }

__global__ void convert_x(const float* __restrict__ x, __hip_bfloat16* __restrict__ xbf) {
    const int gid = blockIdx.x * blockDim.x + threadIdx.x;
    const float4 v = reinterpret_cast<const float4*>(x)[gid];
    __hip_bfloat16* d = xbf + 4 * (size_t)gid;
    d[0] = __float2bfloat16(v.x); d[1] = __float2bfloat16(v.y);
    d[2] = __float2bfloat16(v.z); d[3] = __float2bfloat16(v.w);
}

// 48 persistent blocks x 256 threads; per-WAVE flags (64 per stage), no
// __syncthreads / threadfence / cache invalidation in the steady-state loop.
//   bid  0..15 : phi-blocks — 32 cols of phi; x-part GEMM overlaps the r-wait
//   bid 16..31 : s-blocks   — 16 cols of r;   s_a = mu_a @ W1_a^T in regs
//   bid 32..47 : o-blocks   — 16 cols of out; o_a = mu_a @ Wo_a^T in regs
// Flag idx = producer_block*4 + wave (wave w owns batch rows [32w, 32w+32)).
__global__ void __launch_bounds__(256) sru_pipe(
    const float* __restrict__ W1, const float* __restrict__ W2,
    const float* __restrict__ Wo,
    const float* __restrict__ b1, const float* __restrict__ b2,
    const float* __restrict__ bo,
    const __hip_bfloat16* __restrict__ xbf,
    __hip_bfloat16* __restrict__ rbf,
    __hip_bfloat16* __restrict__ phib,
    float* __restrict__ out, int* __restrict__ ctrl)
{
    __shared__ __hip_bfloat16 wlds[32768];   // 64 KB
    const int bid  = blockIdx.x;
    const int tid  = threadIdx.x;
    const int wave = tid >> 6;
    const int lane = tid & 63;
    const int quad = lane >> 4;
    const int lrow = lane & 15;
    const int m0   = wave * 32;
    int* rfl = ctrl;         // 64 flags
    int* pfl = ctrl + 64;    // 64 flags
    int* ofl = ctrl + 128;   // 64 flags
    const float pre[4]  = {0.f, 1.f, 9.f, 99.f};    // alpha/(1-alpha)
    const float post[4] = {1.f, 0.5f, 0.1f, 0.01f}; // (1-alpha)

    if (bid < 16) {
        // ================= phi-block =================
        const int j0 = bid * 32;
        for (int i = tid * 4; i < 2 * 32 * 256; i += 1024) {
            const int part = i >> 13, rem = i & 8191;
            const int n = rem >> 8, k = rem & 255;
            const float4 v = *reinterpret_cast<const float4*>(
                &W2[(j0 + n) * (XD + RD) + part * 256 + k]);
            __hip_bfloat16* dst = &wlds[(((part * 32 + (k >> 3)) * 32 + n) << 3) + (k & 7)];
            dst[0] = __float2bfloat16(v.x); dst[1] = __float2bfloat16(v.y);
            dst[2] = __float2bfloat16(v.z); dst[3] = __float2bfloat16(v.w);
        }
        __syncthreads();
        const float bj0 = b2[j0 + lrow];
        const float bj1 = b2[j0 + 16 + lrow];
        #pragma unroll 1
        for (int t = 0; t < SEQ; ++t) {
            floatx4 acc[2][2] = {};
            // x-part (cached loads; no dependency on r_t) — overlaps the wait
            const __hip_bfloat16* xt = xbf + (size_t)(t * BATCH + m0) * XD;
            #pragma unroll
            for (int k = 0; k < XD; k += 32) {
                const short8 a0 = ldg8(xt + lrow * XD + k + 8 * quad);
                const short8 a1 = ldg8(xt + (16 + lrow) * XD + k + 8 * quad);
                #pragma unroll
                for (int j2 = 0; j2 < 2; ++j2) {
                    const short8 b = ldg8(&wlds[((((k >> 3) + quad) * 32 + j2 * 16 + lrow) << 3)]);
                    acc[0][j2] = MFMA(a0, b, acc[0][j2]);
                    acc[1][j2] = MFMA(a1, b, acc[1][j2]);
                }
            }
            // wait r_t (16 s-waves for rows m0..m0+32) + o back-pressure on ring
            if (lane < 16) {
                const int* f = &rfl[lane * 4 + wave];
                while (flagld(f) < t + 1) {}
            } else if (lane < 32) {
                const int* f = &ofl[(lane - 16) * 4 + wave];
                while (flagld(f) < t - 3) {}
            }
            cbar();
            // r-part (coherent concurrent loads)
            #pragma unroll 4
            for (int k = 0; k < RD; k += 32) {
                const short8 a0 = lda16(rbf + (m0 + lrow) * RD + k + 8 * quad);
                const short8 a1 = lda16(rbf + (m0 + 16 + lrow) * RD + k + 8 * quad);
                #pragma unroll
                for (int j2 = 0; j2 < 2; ++j2) {
                    const short8 b = ldg8(&wlds[(((32 + (k >> 3) + quad) * 32 + j2 * 16 + lrow) << 3)]);
                    acc[0][j2] = MFMA(a0, b, acc[0][j2]);
                    acc[1][j2] = MFMA(a1, b, acc[1][j2]);
                }
            }
            __hip_bfloat16* pb = phib + (size_t)(t & 3) * BATCH * PHID;
            #pragma unroll
            for (int h = 0; h < 2; ++h)
                #pragma unroll
                for (int j2 = 0; j2 < 2; ++j2)
                    #pragma unroll
                    for (int i = 0; i < 4; ++i) {
                        const int row = m0 + 16 * h + quad * 4 + i;
                        const float v = (h ? acc[1][j2][i] : acc[0][j2][i]) + (j2 ? bj1 : bj0);
                        sta2(&pb[row * PHID + j0 + j2 * 16 + lrow], fmaxf(v, 0.f));
                    }
            drain();
            if (lane == 0) flagst(&pfl[bid * 4 + wave], t + 1);
        }
    } else if (bid < 32) {
        // ================= s-block =================
        const int sb = bid - 16, j0 = sb * 16;
        for (int i = tid * 4; i < 4 * 16 * 512; i += 1024) {
            const int a = i >> 13, rem = i & 8191;
            const int n = rem >> 9, k = rem & 511;
            const float4 v = *reinterpret_cast<const float4*>(
                &W1[(j0 + n) * 2048 + a * 512 + k]);
            __hip_bfloat16* dst = &wlds[(((a * 64 + (k >> 3)) * 16 + n) << 3) + (k & 7)];
            dst[0] = __float2bfloat16(v.x); dst[1] = __float2bfloat16(v.y);
            dst[2] = __float2bfloat16(v.z); dst[3] = __float2bfloat16(v.w);
        }
        __syncthreads();
        const float bjv = b1[j0 + lrow];
        floatx4 s[4][2] = {};
        // publish r_0 = relu(b1)
        {
            const float rv = fmaxf(bjv, 0.f);
            #pragma unroll
            for (int h = 0; h < 2; ++h)
                #pragma unroll
                for (int i = 0; i < 4; ++i)
                    sta2(&rbf[(m0 + 16 * h + quad * 4 + i) * RD + j0 + lrow], rv);
            drain();
            if (lane == 0) flagst(&rfl[sb * 4 + wave], 1);
        }
        #pragma unroll 1
        for (int t = 0; t < SEQ; ++t) {
            if (lane < 16) {
                const int* f = &pfl[lane * 4 + wave];
                while (flagld(f) < t + 1) {}
            }
            cbar();
            #pragma unroll
            for (int a = 0; a < 4; ++a) { s[a][0] *= pre[a]; s[a][1] *= pre[a]; }
            const __hip_bfloat16* pb = phib + (size_t)(t & 3) * BATCH * PHID;
            #pragma unroll 4
            for (int k = 0; k < PHID; k += 32) {
                const short8 a0 = lda16(pb + (m0 + lrow) * PHID + k + 8 * quad);
                const short8 a1 = lda16(pb + (m0 + 16 + lrow) * PHID + k + 8 * quad);
                #pragma unroll
                for (int a = 0; a < 4; ++a) {
                    const short8 b = ldg8(&wlds[(((a * 64 + (k >> 3) + quad) * 16 + lrow) << 3)]);
                    s[a][0] = MFMA(a0, b, s[a][0]);
                    s[a][1] = MFMA(a1, b, s[a][1]);
                }
            }
            #pragma unroll
            for (int a = 0; a < 4; ++a) { s[a][0] *= post[a]; s[a][1] *= post[a]; }
            if (t < SEQ - 1) {
                #pragma unroll
                for (int h = 0; h < 2; ++h)
                    #pragma unroll
                    for (int i = 0; i < 4; ++i) {
                        const float rv = s[0][h][i] + s[1][h][i] + s[2][h][i] + s[3][h][i] + bjv;
                        sta2(&rbf[(m0 + 16 * h + quad * 4 + i) * RD + j0 + lrow], fmaxf(rv, 0.f));
                    }
                drain();
                if (lane == 0) flagst(&rfl[sb * 4 + wave], t + 2);
            }
        }
    } else {
        // ================= o-block =================
        const int ob = bid - 32, j0 = ob * 16;
        for (int i = tid * 4; i < 4 * 16 * 512; i += 1024) {
            const int a = i >> 13, rem = i & 8191;
            const int n = rem >> 9, k = rem & 511;
            const float4 v = *reinterpret_cast<const float4*>(
                &Wo[(j0 + n) * 2048 + a * 512 + k]);
            __hip_bfloat16* dst = &wlds[(((a * 64 + (k >> 3)) * 16 + n) << 3) + (k & 7)];
            dst[0] = __float2bfloat16(v.x); dst[1] = __float2bfloat16(v.y);
            dst[2] = __float2bfloat16(v.z); dst[3] = __float2bfloat16(v.w);
        }
        __syncthreads();
        floatx4 o[4][2] = {};
        #pragma unroll 1
        for (int t = 0; t < SEQ; ++t) {
            if (lane < 16) {
                const int* f = &pfl[lane * 4 + wave];
                while (flagld(f) < t + 1) {}
            }
            cbar();
            #pragma unroll
            for (int a = 0; a < 4; ++a) { o[a][0] *= pre[a]; o[a][1] *= pre[a]; }
            const __hip_bfloat16* pb = phib + (size_t)(t & 3) * BATCH * PHID;
            #pragma unroll 4
            for (int k = 0; k < PHID; k += 32) {
                const short8 a0 = lda16(pb + (m0 + lrow) * PHID + k + 8 * quad);
                const short8 a1 = lda16(pb + (m0 + 16 + lrow) * PHID + k + 8 * quad);
                #pragma unroll
                for (int a = 0; a < 4; ++a) {
                    const short8 b = ldg8(&wlds[(((a * 64 + (k >> 3) + quad) * 16 + lrow) << 3)]);
                    o[a][0] = MFMA(a0, b, o[a][0]);
                    o[a][1] = MFMA(a1, b, o[a][1]);
                }
            }
            #pragma unroll
            for (int a = 0; a < 4; ++a) { o[a][0] *= post[a]; o[a][1] *= post[a]; }
            drain();   // loads retired -> safe to free ring slot
            if (lane == 0) flagst(&ofl[ob * 4 + wave], t + 1);
        }
        const float bjo = bo[j0 + lrow];
        #pragma unroll
        for (int h = 0; h < 2; ++h)
            #pragma unroll
            for (int i = 0; i < 4; ++i) {
                const int row = m0 + 16 * h + quad * 4 + i;
                const float v = o[0][h][i] + o[1][h][i] + o[2][h][i] + o[3][h][i] + bjo;
                out[row * OUTD + j0 + lrow] = fmaxf(v, 0.f);
            }
    }
}

extern "C" void kernel_launch(void* const* d_in, const int* in_sizes, int n_in,
                              void* d_out, int out_size, void* d_ws, size_t ws_size,
                              hipStream_t stream)
{
    const float* x  = (const float*)d_in[0];
    const float* W1 = (const float*)d_in[1];
    const float* b1 = (const float*)d_in[2];
    const float* W2 = (const float*)d_in[3];
    const float* b2 = (const float*)d_in[4];
    const float* Wo = (const float*)d_in[5];
    const float* bo = (const float*)d_in[6];
    float* out = (float*)d_out;
    char* ws = (char*)d_ws;

    constexpr size_t O_CTRL = 0;                                 // 192 int flags
    constexpr size_t O_RBF  = 4096;                              // 128x256 bf16 = 64 KB
    constexpr size_t O_PHI  = O_RBF + (size_t)BATCH * RD * 2;    // 4 x 128x512 bf16
    constexpr size_t O_X    = O_PHI + 4ull * BATCH * PHID * 2;   // 32 MB

    hipMemsetAsync(ws + O_CTRL, 0, 4096, stream);
    convert_x<<<SEQ * BATCH * XD / 4 / 256, 256, 0, stream>>>(
        x, (__hip_bfloat16*)(ws + O_X));
    sru_pipe<<<NBLK, 256, 0, stream>>>(
        W1, W2, Wo, b1, b2, bo,
        (const __hip_bfloat16*)(ws + O_X),
        (__hip_bfloat16*)(ws + O_RBF),
        (__hip_bfloat16*)(ws + O_PHI),
        out, (int*)(ws + O_CTRL));
}

// Round 5
// 8300.256 us; speedup vs baseline: 1.7544x; 1.0709x over previous
//
#include <hip/hip_runtime.h>
#include <hip/hip_bf16.h>

#define SEQ   512
#define BATCH 128
#define XD    256
#define PHID  512
#define RD    256
#define OUTD  256
#define NBLK  32

typedef __attribute__((ext_vector_type(8))) short short8;
typedef __attribute__((ext_vector_type(4))) float floatx4;
typedef unsigned long long u64;

#define MFMA(a, b, c) __builtin_amdgcn_mfma_f32_16x16x32_bf16((a), (b), (c), 0, 0, 0)

__device__ inline short8 ldg8(const __hip_bfloat16* p) {       // cached (x, LDS)
    return *reinterpret_cast<const short8*>(p);
}
// Device-coherent 16B fragment load = two relaxed agent-scope 8B atomic loads
// (global_load_dwordx2 sc1: L2-bypass -> LLC coherent point, no waitcnt).
__device__ inline short8 lda16(const __hip_bfloat16* p) {
    union { u64 u[2]; short8 s; } c;
    c.u[0] = __hip_atomic_load((const u64*)p,     __ATOMIC_RELAXED, __HIP_MEMORY_SCOPE_AGENT);
    c.u[1] = __hip_atomic_load((const u64*)p + 1, __ATOMIC_RELAXED, __HIP_MEMORY_SCOPE_AGENT);
    return c.s;
}
// Device-coherent 2B store (write-through to LLC), relaxed -> no waitcnt.
__device__ inline void sta2(__hip_bfloat16* p, float v) {
    union { __hip_bfloat16 b; unsigned short u; } c;
    c.b = __float2bfloat16(v);
    __hip_atomic_store((unsigned short*)p, c.u, __ATOMIC_RELAXED, __HIP_MEMORY_SCOPE_AGENT);
}
__device__ inline int flagld(const int* p) {
    return __hip_atomic_load(p, __ATOMIC_RELAXED, __HIP_MEMORY_SCOPE_AGENT);
}
__device__ inline void flagst(int* p, int v) {
    __hip_atomic_store(p, v, __ATOMIC_RELAXED, __HIP_MEMORY_SCOPE_AGENT);
}
// Drain all outstanding vmem (sc1 stores ack from the coherent point, so
// vmcnt(0) == globally visible). Memory clobber pins the flag store after it.
__device__ inline void drain() { asm volatile("s_waitcnt vmcnt(0)" ::: "memory"); }
__device__ inline void cbar()  { asm volatile("" ::: "memory"); }

__global__ void convert_x(const float* __restrict__ x, __hip_bfloat16* __restrict__ xbf) {
    const int gid = blockIdx.x * blockDim.x + threadIdx.x;
    const float4 v = reinterpret_cast<const float4*>(x)[gid];
    __hip_bfloat16* d = xbf + 4 * (size_t)gid;
    d[0] = __float2bfloat16(v.x); d[1] = __float2bfloat16(v.y);
    d[2] = __float2bfloat16(v.z); d[3] = __float2bfloat16(v.w);
}

// 32 persistent blocks x 256 threads; per-WAVE flags; wave w of every block
// owns batch rows [32w, 32w+32) -- four independent row-group pipelines.
//   bid  0..15 : phi-blocks — 32 cols of phi; x-part GEMM overlaps the r-wait
//   bid 16..31 : s-blocks   — 16 cols of r AND 16 cols of out;
//                s_a = mu_a@W1_a^T and o_a = mu_a@Wo_a^T both in registers;
//                phi fragments loaded ONCE feed both; o-MFMAs run after the
//                r-publish (off the critical path).
// All cross-block data via relaxed sc1 atomics (LLC coherent), all a-fragment
// loads issued in ONE batch before any MFMA -> single LLC round trip per hop.
__global__ void __launch_bounds__(256, 1) sru_pipe(
    const float* __restrict__ W1, const float* __restrict__ W2,
    const float* __restrict__ Wo,
    const float* __restrict__ b1, const float* __restrict__ b2,
    const float* __restrict__ bo,
    const __hip_bfloat16* __restrict__ xbf,
    __hip_bfloat16* __restrict__ rbf,
    __hip_bfloat16* __restrict__ phib,
    float* __restrict__ out, int* __restrict__ ctrl)
{
    __shared__ __hip_bfloat16 wlds[65536];   // 128 KB (s-blocks: W1 + Wo)
    const int bid  = blockIdx.x;
    const int tid  = threadIdx.x;
    const int wave = tid >> 6;
    const int lane = tid & 63;
    const int quad = lane >> 4;
    const int lrow = lane & 15;
    const int m0   = wave * 32;
    int* rfl = ctrl;         // 64 flags: r availability  (value = t+1)
    int* pfl = ctrl + 64;    // 64 flags: phi availability (value = t+1)
    const float pre[4]  = {0.f, 1.f, 9.f, 99.f};    // alpha/(1-alpha)
    const float post[4] = {1.f, 0.5f, 0.1f, 0.01f}; // (1-alpha)

    if (bid < 16) {
        // ================= phi-block =================
        const int j0 = bid * 32;
        for (int i = tid * 4; i < 2 * 32 * 256; i += 1024) {
            const int part = i >> 13, rem = i & 8191;
            const int n = rem >> 8, k = rem & 255;
            const float4 v = *reinterpret_cast<const float4*>(
                &W2[(j0 + n) * (XD + RD) + part * 256 + k]);
            __hip_bfloat16* dst = &wlds[(((part * 32 + (k >> 3)) * 32 + n) << 3) + (k & 7)];
            dst[0] = __float2bfloat16(v.x); dst[1] = __float2bfloat16(v.y);
            dst[2] = __float2bfloat16(v.z); dst[3] = __float2bfloat16(v.w);
        }
        __syncthreads();
        const float bj0 = b2[j0 + lrow];
        const float bj1 = b2[j0 + 16 + lrow];
        #pragma unroll 1
        for (int t = 0; t < SEQ; ++t) {
            floatx4 acc[2][2] = {};
            // x-part (cached loads; no dependency on r_t) — overlaps the wait
            const __hip_bfloat16* xt = xbf + (size_t)(t * BATCH + m0) * XD;
            #pragma unroll
            for (int k = 0; k < XD; k += 32) {
                const short8 a0 = ldg8(xt + lrow * XD + k + 8 * quad);
                const short8 a1 = ldg8(xt + (16 + lrow) * XD + k + 8 * quad);
                #pragma unroll
                for (int j2 = 0; j2 < 2; ++j2) {
                    const short8 b = ldg8(&wlds[((((k >> 3) + quad) * 32 + j2 * 16 + lrow) << 3)]);
                    acc[0][j2] = MFMA(a0, b, acc[0][j2]);
                    acc[1][j2] = MFMA(a1, b, acc[1][j2]);
                }
            }
            // wait r_t (16 s-block waves covering rows m0..m0+32)
            if (lane < 16) {
                const int* f = &rfl[lane * 4 + wave];
                while (flagld(f) < t + 1) {}
            }
            cbar();
            // r-part: issue ALL 16 coherent loads, then MFMA (1 LLC round trip)
            short8 ra[2][8];
            {
                const __hip_bfloat16* r0 = rbf + (m0 + lrow) * RD + 8 * quad;
                const __hip_bfloat16* r1 = rbf + (m0 + 16 + lrow) * RD + 8 * quad;
                #pragma unroll
                for (int j = 0; j < 8; ++j) {
                    ra[0][j] = lda16(r0 + 32 * j);
                    ra[1][j] = lda16(r1 + 32 * j);
                }
            }
            #pragma unroll
            for (int j = 0; j < 8; ++j) {
                #pragma unroll
                for (int j2 = 0; j2 < 2; ++j2) {
                    const short8 b = ldg8(&wlds[(((32 + 4 * j + quad) * 32 + j2 * 16 + lrow) << 3)]);
                    acc[0][j2] = MFMA(ra[0][j], b, acc[0][j2]);
                    acc[1][j2] = MFMA(ra[1][j], b, acc[1][j2]);
                }
            }
            __hip_bfloat16* pb = phib + (size_t)(t & 3) * BATCH * PHID;
            #pragma unroll
            for (int h = 0; h < 2; ++h)
                #pragma unroll
                for (int j2 = 0; j2 < 2; ++j2)
                    #pragma unroll
                    for (int i = 0; i < 4; ++i) {
                        const int row = m0 + 16 * h + quad * 4 + i;
                        const float v = (h ? acc[1][j2][i] : acc[0][j2][i]) + (j2 ? bj1 : bj0);
                        sta2(&pb[row * PHID + j0 + j2 * 16 + lrow], fmaxf(v, 0.f));
                    }
            drain();
            if (lane == 0) flagst(&pfl[bid * 4 + wave], t + 1);
        }
    } else {
        // ================= s-block (s + o fused) =================
        const int sb = bid - 16, j0 = sb * 16;
        for (int i = tid * 4; i < 65536; i += 1024) {
            const int mtx = i >> 15;                 // 0 = W1, 1 = Wo
            const int r3 = i & 32767;
            const int a = r3 >> 13, rem = r3 & 8191;
            const int n = rem >> 9, k = rem & 511;
            const float* src = mtx ? Wo : W1;
            const float4 v = *reinterpret_cast<const float4*>(
                &src[(j0 + n) * 2048 + a * 512 + k]);
            __hip_bfloat16* dst = &wlds[mtx * 32768 + (((a * 64 + (k >> 3)) * 16 + n) << 3) + (k & 7)];
            dst[0] = __float2bfloat16(v.x); dst[1] = __float2bfloat16(v.y);
            dst[2] = __float2bfloat16(v.z); dst[3] = __float2bfloat16(v.w);
        }
        __syncthreads();
        const float bjv = b1[j0 + lrow];
        floatx4 s[4][2] = {};
        floatx4 o[4][2] = {};
        // publish r_0 = relu(b1)
        {
            const float rv = fmaxf(bjv, 0.f);
            #pragma unroll
            for (int h = 0; h < 2; ++h)
                #pragma unroll
                for (int i = 0; i < 4; ++i)
                    sta2(&rbf[(m0 + 16 * h + quad * 4 + i) * RD + j0 + lrow], rv);
            drain();
            if (lane == 0) flagst(&rfl[sb * 4 + wave], 1);
        }
        #pragma unroll 1
        for (int t = 0; t < SEQ; ++t) {
            if (lane < 16) {
                const int* f = &pfl[lane * 4 + wave];
                while (flagld(f) < t + 1) {}
            }
            cbar();
            // issue ALL 32 coherent phi loads (1 LLC round trip), then MFMA
            short8 pa[2][16];
            {
                const __hip_bfloat16* pb = phib + (size_t)(t & 3) * BATCH * PHID;
                const __hip_bfloat16* p0 = pb + (m0 + lrow) * PHID + 8 * quad;
                const __hip_bfloat16* p1 = pb + (m0 + 16 + lrow) * PHID + 8 * quad;
                #pragma unroll
                for (int j = 0; j < 16; ++j) {
                    pa[0][j] = lda16(p0 + 32 * j);
                    pa[1][j] = lda16(p1 + 32 * j);
                }
            }
            #pragma unroll
            for (int a = 0; a < 4; ++a) { s[a][0] *= pre[a]; s[a][1] *= pre[a]; }
            #pragma unroll
            for (int j = 0; j < 16; ++j) {
                #pragma unroll
                for (int a = 0; a < 4; ++a) {
                    const short8 b = ldg8(&wlds[(((a * 64 + 4 * j + quad) * 16 + lrow) << 3)]);
                    s[a][0] = MFMA(pa[0][j], b, s[a][0]);
                    s[a][1] = MFMA(pa[1][j], b, s[a][1]);
                }
            }
            #pragma unroll
            for (int a = 0; a < 4; ++a) { s[a][0] *= post[a]; s[a][1] *= post[a]; }
            // publish r_{t+1} ASAP (critical path), then do o off-path
            if (t < SEQ - 1) {
                #pragma unroll
                for (int h = 0; h < 2; ++h)
                    #pragma unroll
                    for (int i = 0; i < 4; ++i) {
                        const float rv = s[0][h][i] + s[1][h][i] + s[2][h][i] + s[3][h][i] + bjv;
                        sta2(&rbf[(m0 + 16 * h + quad * 4 + i) * RD + j0 + lrow], fmaxf(rv, 0.f));
                    }
                drain();
                if (lane == 0) flagst(&rfl[sb * 4 + wave], t + 2);
            }
            // o-update reusing the already-loaded phi fragments
            #pragma unroll
            for (int a = 0; a < 4; ++a) { o[a][0] *= pre[a]; o[a][1] *= pre[a]; }
            #pragma unroll
            for (int j = 0; j < 16; ++j) {
                #pragma unroll
                for (int a = 0; a < 4; ++a) {
                    const short8 b = ldg8(&wlds[32768 + (((a * 64 + 4 * j + quad) * 16 + lrow) << 3)]);
                    o[a][0] = MFMA(pa[0][j], b, o[a][0]);
                    o[a][1] = MFMA(pa[1][j], b, o[a][1]);
                }
            }
            #pragma unroll
            for (int a = 0; a < 4; ++a) { o[a][0] *= post[a]; o[a][1] *= post[a]; }
        }
        const float bjo = bo[j0 + lrow];
        #pragma unroll
        for (int h = 0; h < 2; ++h)
            #pragma unroll
            for (int i = 0; i < 4; ++i) {
                const int row = m0 + 16 * h + quad * 4 + i;
                const float v = o[0][h][i] + o[1][h][i] + o[2][h][i] + o[3][h][i] + bjo;
                out[row * OUTD + j0 + lrow] = fmaxf(v, 0.f);
            }
    }
}

extern "C" void kernel_launch(void* const* d_in, const int* in_sizes, int n_in,
                              void* d_out, int out_size, void* d_ws, size_t ws_size,
                              hipStream_t stream)
{
    const float* x  = (const float*)d_in[0];
    const float* W1 = (const float*)d_in[1];
    const float* b1 = (const float*)d_in[2];
    const float* W2 = (const float*)d_in[3];
    const float* b2 = (const float*)d_in[4];
    const float* Wo = (const float*)d_in[5];
    const float* bo = (const float*)d_in[6];
    float* out = (float*)d_out;
    char* ws = (char*)d_ws;

    constexpr size_t O_CTRL = 0;                                 // 128 int flags
    constexpr size_t O_RBF  = 4096;                              // 128x256 bf16 = 64 KB
    constexpr size_t O_PHI  = O_RBF + (size_t)BATCH * RD * 2;    // 4 x 128x512 bf16
    constexpr size_t O_X    = O_PHI + 4ull * BATCH * PHID * 2;   // 32 MB

    hipMemsetAsync(ws + O_CTRL, 0, 4096, stream);
    convert_x<<<SEQ * BATCH * XD / 4 / 256, 256, 0, stream>>>(
        x, (__hip_bfloat16*)(ws + O_X));
    sru_pipe<<<NBLK, 256, 0, stream>>>(
        W1, W2, Wo, b1, b2, bo,
        (const __hip_bfloat16*)(ws + O_X),
        (__hip_bfloat16*)(ws + O_RBF),
        (__hip_bfloat16*)(ws + O_PHI),
        out, (int*)(ws + O_CTRL));
}